// Round 4
// baseline (321.710 us; speedup 1.0000x reference)
//
#include <hip/hip_runtime.h>
#include <math.h>

// Problem: B=4, S=4096, H=2048, E=64, K=8; T = 16384 tokens.
#define HDIM 2048
#define TTOK 16384
#define NEXP 64
#define TOPK 8
#define SLEN 4096
#define NBATCH 4

// Output layout (flat, float32):
#define OFF_W    131072
#define OFF_LOSS 262144
#define OFF_LOAD 262145

// ws layout (float offsets): Pacc[4][64] @0, Cacc[4][64] @256, counter @512,
// WF (frag-ordered bf16 W planes) @1024: 2 planes x 32 kt x 4 nt x 2 reg x
// 64 lane x 8 ushort = 262144 ushorts (512 KB).
#define WS_PACC 0
#define WS_CACC 256
#define WS_CNT  512
#define WS_WF   1024
#define WFLO    131072  // ushort offset of lo plane within WF
#define NBLK    1024    // gate_fused grid

using s16x8 = __attribute__((ext_vector_type(8))) short;   // 8 bf16 (4 VGPR)
using f32x4 = __attribute__((ext_vector_type(4))) float;   // MFMA acc

// bf16 round-to-nearest-even of fp32 (finite inputs only)
__device__ __forceinline__ unsigned bfh(float v) {
  unsigned b = __float_as_uint(v);
  return (b + 0x7FFFu + ((b >> 16) & 1u)) >> 16;
}

// split float4 into hi/lo bf16 planes, packed 4x bf16 per uint2
__device__ __forceinline__ void split4(float4 v, uint2* hi, uint2* lo) {
  unsigned h0 = bfh(v.x), h1 = bfh(v.y), h2 = bfh(v.z), h3 = bfh(v.w);
  float r0 = v.x - __uint_as_float(h0 << 16);
  float r1 = v.y - __uint_as_float(h1 << 16);
  float r2 = v.z - __uint_as_float(h2 << 16);
  float r3 = v.w - __uint_as_float(h3 << 16);
  unsigned l0 = bfh(r0), l1 = bfh(r1), l2 = bfh(r2), l3 = bfh(r3);
  *hi = make_uint2(h0 | (h1 << 16), h2 | (h3 << 16));
  *lo = make_uint2(l0 | (l1 << 16), l2 | (l3 << 16));
}

// ---------------------------------------------------------------------------
// W fp32 [64][2048] -> WF: B-frag-ordered bf16 planes.
// WF index (ushort/8): ((plane*32 + kt)*4 + nt)*2 + reg, then lane, then 8 k.
// Lane (fl=lane&15, fg=lane>>4) holds W[nt*16+fl][kt*64 + reg*32 + fg*8 ..+8]
// == exactly R3's proven B-frag (swizzled-LDS read result), k ascending.
__global__ __launch_bounds__(256) void prep_wf(const float* __restrict__ W,
                                               ushort* __restrict__ WF) {
  const int id = blockIdx.x * 256 + threadIdx.x;  // grid 128 -> 32768
  const int lane = id & 63;
  const int reg = (id >> 6) & 1;
  const int nt = (id >> 7) & 3;
  const int kt = (id >> 9) & 31;
  const int plane = id >> 14;  // 0=hi, 1=lo
  const int e = (nt << 4) + (lane & 15);
  const int k0 = (kt << 6) + (reg << 5) + ((lane >> 4) << 3);
  const float* src = W + (size_t)e * HDIM + k0;
  unsigned w[4];
#pragma unroll
  for (int j = 0; j < 4; ++j) {
    float v0 = src[2 * j], v1 = src[2 * j + 1];
    unsigned h0 = bfh(v0), h1 = bfh(v1);
    if (plane) {
      h0 = bfh(v0 - __uint_as_float(h0 << 16));
      h1 = bfh(v1 - __uint_as_float(h1 << 16));
    }
    w[j] = h0 | (h1 << 16);
  }
  *(uint4*)(WF + ((size_t)id << 3)) = make_uint4(w[0], w[1], w[2], w[3]);
}

// ---------------------------------------------------------------------------
// Fused gate, high-occupancy form: grid 1024 x 256 thr = 4 waves.
// Block = 16 tokens x 64 experts x full K. Wave nt: one 16x16 MFMA tile
// (tokens 0..15 x experts [16nt,16nt+16)), 3-term bf16-split, 6 MFMA/step.
// 8 blocks/CU (launch_bounds 256,8; LDS ~17KB) -> vmcnt(0) barrier drains
// of one block overlap with 7 others' compute (R0-regime latency hiding).
// x staged in LDS (hi/lo bf16, XOR-granule swizzle, R3-proven formulas);
// W read per-wave from global in frag order (L1/L2-resident, coalesced).
// MFMA term/step order identical to R3 -> same FP result family.
__global__ __launch_bounds__(256, 8) void gate_fused(
    const float* __restrict__ x,    // [16384][2048]
    const ushort* __restrict__ WF,  // frag-ordered bf16 planes
    const float* __restrict__ bias, // [64]
    float* __restrict__ out, float* __restrict__ Pacc,
    float* __restrict__ Cacc, int* __restrict__ counter) {
  __shared__ ushort XhL[2][1024];  // [16 tok][64 k] swizzled, 2 KB each
  __shared__ ushort XlL[2][1024];
  __shared__ float le[16 * 65];    // logits [token][expert], padded
  __shared__ float sgm[16 * 65];   // sigmoid(logits), padded
  __shared__ float rinvs[16];
  __shared__ float biasl[64];
  __shared__ unsigned csum[64];
  __shared__ int lastf;

  const int tid = threadIdx.x;
  const int lane = tid & 63;
  const int nt = __builtin_amdgcn_readfirstlane(tid >> 6);  // 0..3
  const int tok0 = blockIdx.x << 4;  // 16 tokens/block, 1024 blocks

  if (tid < 64) { csum[tid] = 0u; biasl[tid] = bias[tid]; }

  // ---- staging map: thread -> row (tid>>4, 0..15), k-offset (tid&15)*4 ----
  const int srow = tid >> 4;
  const int skq = (tid & 15) << 2;
  const int sdst = (srow << 6) + (((skq >> 3) ^ (srow & 7)) << 3) +
                   (((skq >> 2) & 1) << 2);  // ushort index
  const float* xsrc = x + (size_t)(tok0 + srow) * HDIM + skq;
  float4 xA = *(const float4*)xsrc;          // step 0
  float4 xB = *(const float4*)(xsrc + 64);   // step 1

  // ---- MFMA frag addressing (wave nt; A from LDS, B from global WF) ----
  const int fl = lane & 15, fg = lane >> 4;
  const int arow = fl;  // token row 0..15
  const int ab0 = (arow << 6) + ((fg ^ (arow & 7)) << 3);        // k 0..31
  const int ab1 = (arow << 6) + (((fg + 4) ^ (arow & 7)) << 3);  // k 32..63
  const ushort* wbase = WF + ((size_t)((nt << 7) + lane) << 3);

  f32x4 acc = {0.f, 0.f, 0.f, 0.f};

  constexpr int NT = HDIM / 64;  // 32 steps of K=64
  for (int kt = 0; kt < NT; ++kt) {
    const int cur = kt & 1;
    {  // convert + stage x hi/lo (writes buf[cur])
      uint2 hp, lp;
      split4(xA, &hp, &lp);
      *(uint2*)&XhL[cur][sdst] = hp;
      *(uint2*)&XlL[cur][sdst] = lp;
    }
    __syncthreads();  // single barrier/step (dbuf-proven)
    xA = xB;
    if (kt + 2 < NT) xB = *(const float4*)(xsrc + ((kt + 2) << 6));
    // B-frags from global (frag-ordered; kt stride = 4096 ushorts)
    const ushort* whp = wbase + (kt << 12);
    s16x8 bh0 = *(const s16x8*)whp;
    s16x8 bh1 = *(const s16x8*)(whp + 512);
    s16x8 bl0 = *(const s16x8*)(whp + WFLO);
    s16x8 bl1 = *(const s16x8*)(whp + WFLO + 512);
    // A-frags from LDS
    s16x8 ah0 = *(const s16x8*)&XhL[cur][ab0];
    s16x8 al0 = *(const s16x8*)&XlL[cur][ab0];
    s16x8 ah1 = *(const s16x8*)&XhL[cur][ab1];
    s16x8 al1 = *(const s16x8*)&XlL[cur][ab1];
    // identical term order to R3: (al*bh, ah*bl, ah*bh) per K-half
    acc = __builtin_amdgcn_mfma_f32_16x16x32_bf16(al0, bh0, acc, 0, 0, 0);
    acc = __builtin_amdgcn_mfma_f32_16x16x32_bf16(ah0, bl0, acc, 0, 0, 0);
    acc = __builtin_amdgcn_mfma_f32_16x16x32_bf16(ah0, bh0, acc, 0, 0, 0);
    acc = __builtin_amdgcn_mfma_f32_16x16x32_bf16(al1, bh1, acc, 0, 0, 0);
    acc = __builtin_amdgcn_mfma_f32_16x16x32_bf16(ah1, bl1, acc, 0, 0, 0);
    acc = __builtin_amdgcn_mfma_f32_16x16x32_bf16(ah1, bh1, acc, 0, 0, 0);
  }

  // ---- publish logits + sigmoids (C/D: row=fg*4+r (token), col=fl) ----
  {
    const int trow = fg << 2;
    const int ecol = (nt << 4) + fl;
#pragma unroll
    for (int r = 0; r < 4; ++r) {
      float lg = acc[r];
      le[(trow + r) * 65 + ecol] = lg;
      sgm[(trow + r) * 65 + ecol] = 1.f / (1.f + expf(-lg));
    }
  }
  __syncthreads();

  const int b = (int)(blockIdx.x >> 8);  // batch (256 blocks/batch)

  if (nt == 0) {
    // per-token top-8 (lane = token, 16 active), proven scan structure
    if (lane < 16) {
      const int t = lane;
      float bl[64];
#pragma unroll
      for (int e = 0; e < NEXP; ++e) bl[e] = le[t * 65 + e] + biasl[e];

      unsigned long long chosen = 0ull;
      int i8[TOPK];
      float w8[TOPK];
      float wsum = 0.f;
#pragma unroll
      for (int j = 0; j < TOPK; ++j) {
        float best = -1e30f;
        int bi = 0;
#pragma unroll
        for (int e = 0; e < NEXP; ++e) {
          bool ok = (((chosen >> e) & 1ull) == 0ull) && (bl[e] > best);
          if (ok) { best = bl[e]; bi = e; }
        }
        chosen |= (1ull << bi);
        float sc = sgm[t * 65 + bi];
        i8[j] = bi;
        w8[j] = sc;
        wsum += sc;
      }
      const float inv = 1.f / (wsum + 1e-10f);
      const int tt = tok0 + t;
      float4 o;
      o.x = (float)i8[0]; o.y = (float)i8[1]; o.z = (float)i8[2]; o.w = (float)i8[3];
      *(float4*)(out + (size_t)tt * TOPK) = o;
      o.x = (float)i8[4]; o.y = (float)i8[5]; o.z = (float)i8[6]; o.w = (float)i8[7];
      *(float4*)(out + (size_t)tt * TOPK + 4) = o;
      o.x = w8[0] * inv; o.y = w8[1] * inv; o.z = w8[2] * inv; o.w = w8[3] * inv;
      *(float4*)(out + OFF_W + (size_t)tt * TOPK) = o;
      o.x = w8[4] * inv; o.y = w8[5] * inv; o.z = w8[6] * inv; o.w = w8[7] * inv;
      *(float4*)(out + OFF_W + (size_t)tt * TOPK + 4) = o;
#pragma unroll
      for (int j = 0; j < TOPK; ++j) atomicAdd(&csum[i8[j]], 1u);
    }
    // wave-lockstep: lanes<16's LDS atomics precede this in program order
    atomicAdd(&Cacc[(b << 6) + lane], (float)csum[lane]);
  } else if (nt == 1) {
    // row sums of sigmoids -> rinv (16 tokens), then per-expert P partial
    if (lane < 16) {
      const int t = lane;
      float ss = 0.f;
      for (int e = 0; e < NEXP; ++e) ss += sgm[t * 65 + e];
      rinvs[t] = 1.f / (ss + 1e-10f);
    }
    // same-wave LDS RAW -> ordered via lgkmcnt
    float p = 0.f;
#pragma unroll
    for (int t2 = 0; t2 < 16; ++t2) p += sgm[t2 * 65 + lane] * rinvs[t2];
    atomicAdd(&Pacc[(b << 6) + lane], p);
  }

  __syncthreads();
  __threadfence();
  if (tid == 0) {
    int old = __hip_atomic_fetch_add(counter, 1, __ATOMIC_ACQ_REL,
                                     __HIP_MEMORY_SCOPE_AGENT);
    lastf = (old == NBLK - 1) ? 1 : 0;
  }
  __syncthreads();

  if (lastf && tid < 64) {
    const int e = tid;
    float load = 0.f, partl = 0.f;
#pragma unroll
    for (int bb = 0; bb < NBATCH; ++bb) {
      float c = __hip_atomic_load(&Cacc[(bb << 6) + e], __ATOMIC_RELAXED,
                                  __HIP_MEMORY_SCOPE_AGENT);
      float p = __hip_atomic_load(&Pacc[(bb << 6) + e], __ATOMIC_RELAXED,
                                  __HIP_MEMORY_SCOPE_AGENT);
      load += c;
      partl += (c * (1.f / (TOPK * (float)SLEN))) * (p * (1.f / (float)SLEN));
    }
    out[OFF_LOAD + e] = load;
#pragma unroll
    for (int off = 32; off; off >>= 1) partl += __shfl_down(partl, off);
    if (e == 0) out[OFF_LOSS] = 0.01f * partl * (1.f / (float)NBATCH);
  }
}

// ---------------------------------------------------------------------------
extern "C" void kernel_launch(void* const* d_in, const int* in_sizes, int n_in,
                              void* d_out, int out_size, void* d_ws, size_t ws_size,
                              hipStream_t stream) {
  const float* x = (const float*)d_in[0];     // [4,4096,2048]
  const float* W = (const float*)d_in[1];     // [64,2048]
  const float* bias = (const float*)d_in[2];  // [64]
  float* out = (float*)d_out;

  float* ws = (float*)d_ws;
  float* Pacc = ws + WS_PACC;
  float* Cacc = ws + WS_CACC;
  int* counter = (int*)(ws + WS_CNT);
  ushort* WF = (ushort*)(ws + WS_WF);

  hipMemsetAsync(ws, 0, 1024 * sizeof(float), stream);
  prep_wf<<<128, 256, 0, stream>>>(W, WF);
  gate_fused<<<NBLK, 256, 0, stream>>>(x, WF, bias, out, Pacc, Cacc, counter);
}